// Round 4
// baseline (270.450 us; speedup 1.0000x reference)
//
#include <hip/hip_runtime.h>
#include <hip/hip_bf16.h>
#include <math.h>

#define EPSF 1e-5f

constexpr int D = 128;   // feature dim
constexpr int K = 128;   // centroids
constexpr int BPITCH = 272;   // LDS B-row pitch (bytes): start bank 4*row%32
constexpr int NBLK = 1024;    // persistent grid: 4096 waves = 16/CU at 4 blocks/CU

typedef __bf16 bf16x8 __attribute__((ext_vector_type(8)));
typedef float  f32x4  __attribute__((ext_vector_type(4)));

// ---------------- kernel 1: centroid exp-map -> bf16 + c2 ----------------
__global__ __launch_bounds__(64) void prep_kernel(const float* __restrict__ w,
                                                  __bf16* __restrict__ crb,
                                                  float* __restrict__ c2) {
    int k = blockIdx.x;
    int t = threadIdx.x;
    float a = w[k * D + t];
    float b = w[k * D + t + 64];
    float ss = a * a + b * b;
#pragma unroll
    for (int off = 1; off < 64; off <<= 1)
        ss += __shfl_xor(ss, off, 64);
    float nrm   = sqrtf(ss);
    float nclip = fmaxf(nrm, EPSF);
    float targ  = fminf(nclip, 15.0f);
    float th    = tanhf(targ);
    float s     = th / nclip;
    crb[k * D + t]      = (__bf16)(a * s);
    crb[k * D + t + 64] = (__bf16)(b * s);
    if (t == 0) {
        float cn = s * nrm;
        c2[k] = cn * cn;
    }
}

// ---------------- kernel 2: persistent MFMA pairwise distance ----------------
// 4 waves/block. B staged to LDS once; then a barrier-free grid-stride loop
// over 16-row tiles. Row stats shared via shfl. Column sums accumulated in
// registers across tiles; single block reduction at the end.
__global__ __launch_bounds__(256, 4) void main_kernel(
        const float* __restrict__ x, const float* __restrict__ mask,
        const __bf16* __restrict__ crb, const float* __restrict__ c2g,
        float* __restrict__ out_node, float* __restrict__ partial,
        float* __restrict__ maskpart, int N) {
    __shared__ __align__(16) unsigned char sB[K * BPITCH];  // 34816 B
    __shared__ float sCol[4][K];
    __shared__ float sMaskW[4];

    const int t    = threadIdx.x;
    const int wave = t >> 6;
    const int lane = t & 63;
    const int m    = lane & 15;
    const int q    = lane >> 4;

    // ---- stage B tile into LDS (once) ----
#pragma unroll
    for (int i = 0; i < 8; i++) {
        int f4  = t + 256 * i;        // 2048 float4s of crb
        int row = f4 >> 4;
        int c4  = f4 & 15;
        float4 v = ((const float4*)crb)[f4];
        *(float4*)(sB + row * BPITCH + c4 * 16) = v;
    }

    // ---- per-wave constants: c2 for this lane's 8 columns, hoisted rcp ----
    float c2r[8], rpc[8];
#pragma unroll
    for (int tk = 0; tk < 8; tk++) {
        c2r[tk] = c2g[tk * 16 + m];
        rpc[tk] = __builtin_amdgcn_rcpf(1.0f - c2r[tk]);
    }

    __syncthreads();   // sB published; no barriers after this until the end

    const int ntiles = N >> 4;          // 16-row tiles
    const int stride = NBLK * 4;        // total waves
    float colsum[8] = {0.f, 0.f, 0.f, 0.f, 0.f, 0.f, 0.f, 0.f};
    float masksum = 0.f;

    for (int tile = blockIdx.x * 4 + wave; tile < ntiles; tile += stride) {
        const int rowbase = tile * 16;
        const float* xrow = x + (size_t)(rowbase + m) * D + q * 8;
        float mv = mask[rowbase + m];

        // ---- load + convert + MFMA (per 32-k slab to limit live regs) ----
        f32x4 acc[8] = {};
        float ssq = 0.f;
#pragma unroll
        for (int s = 0; s < 4; s++) {
            float4 a0 = *(const float4*)(xrow + s * 32);
            float4 a1 = *(const float4*)(xrow + s * 32 + 4);
            ssq += a0.x*a0.x + a0.y*a0.y + a0.z*a0.z + a0.w*a0.w
                 + a1.x*a1.x + a1.y*a1.y + a1.z*a1.z + a1.w*a1.w;
            bf16x8 av;
            av[0] = (__bf16)a0.x; av[1] = (__bf16)a0.y;
            av[2] = (__bf16)a0.z; av[3] = (__bf16)a0.w;
            av[4] = (__bf16)a1.x; av[5] = (__bf16)a1.y;
            av[6] = (__bf16)a1.z; av[7] = (__bf16)a1.w;
#pragma unroll
            for (int tk = 0; tk < 8; tk++) {
                bf16x8 bv = *(const bf16x8*)(sB + (tk * 16 + m) * BPITCH + q * 16 + s * 64);
                acc[tk] = __builtin_amdgcn_mfma_f32_16x16x32_bf16(av, bv, acc[tk], 0, 0, 0);
            }
        }

        // full-row sum-sq: combine the 4 quads holding row m's k-chunks
        ssq += __shfl_xor(ssq, 16, 64);
        ssq += __shfl_xor(ssq, 32, 64);
        float rpxm = __builtin_amdgcn_rcpf(1.0f - ssq);   // 1/(1-x2) for row m

        // redistribute row stats to the C-layout rows (q*4+i)
        float x2r[4], rpx[4], mvr[4];
#pragma unroll
        for (int i = 0; i < 4; i++) {
            int src = q * 4 + i;
            x2r[i] = __shfl(ssq,  src, 64);
            rpx[i] = __shfl(rpxm, src, 64);
            mvr[i] = __shfl(mv,   src, 64);
        }
        masksum += mv;   // each row counted 4x (once per quad); /4 later

        // ---- epilogue: acosh distance, immediate streaming store ----
#pragma unroll
        for (int tk = 0; tk < 8; tk++) {
            int col = tk * 16 + m;
            float c2v = c2r[tk];
#pragma unroll
            for (int i = 0; i < 4; i++) {
                float dot = acc[tk][i];
                float sq  = fmaxf(fmaf(-2.0f, dot, x2r[i] + c2v), 0.0f);
                float arg = fmaf(2.0f * sq, rpx[i] * rpc[tk], 1.0f);
                arg = fmaxf(arg, 1.0f + 1e-7f);
                float dist = __logf(arg + __builtin_amdgcn_sqrtf(fmaf(arg, arg, -1.0f)));
                float val = dist * mvr[i];
                colsum[tk] += val;
                int n = rowbase + q * 4 + i;
                __builtin_nontemporal_store(val, &out_node[(size_t)n * K + col]);
            }
        }
    }

    // ---- end-of-kernel block reduction (one barrier) ----
#pragma unroll
    for (int tk = 0; tk < 8; tk++) {
        colsum[tk] += __shfl_xor(colsum[tk], 16, 64);
        colsum[tk] += __shfl_xor(colsum[tk], 32, 64);
    }
    if (lane < 16) {
#pragma unroll
        for (int tk = 0; tk < 8; tk++)
            sCol[wave][tk * 16 + lane] = colsum[tk];
    }
#pragma unroll
    for (int off = 1; off < 64; off <<= 1)
        masksum += __shfl_xor(masksum, off, 64);
    if (lane == 0) sMaskW[wave] = masksum * 0.25f;
    __syncthreads();
    if (t < K)
        partial[(size_t)blockIdx.x * K + t] =
            sCol[0][t] + sCol[1][t] + sCol[2][t] + sCol[3][t];
    if (t == 0)
        maskpart[blockIdx.x] = sMaskW[0] + sMaskW[1] + sMaskW[2] + sMaskW[3];
}

// ---------------- kernel 3: column reduce + divide by mask sum ----------------
__global__ __launch_bounds__(256) void reduce_kernel(
        const float* __restrict__ partial, const float* __restrict__ maskpart,
        float* __restrict__ out_graph, int NB) {
    int k = blockIdx.x;
    int t = threadIdx.x;
    float s = 0.f, mm = 0.f;
    for (int b = t; b < NB; b += 256) {
        s  += partial[(size_t)b * K + k];
        mm += maskpart[b];
    }
#pragma unroll
    for (int off = 1; off < 64; off <<= 1) {
        s  += __shfl_xor(s, off, 64);
        mm += __shfl_xor(mm, off, 64);
    }
    __shared__ float rs[4], rm[4];
    int w = t >> 6;
    if ((t & 63) == 0) { rs[w] = s; rm[w] = mm; }
    __syncthreads();
    if (t == 0) {
        float st = rs[0] + rs[1] + rs[2] + rs[3];
        float mt = rm[0] + rm[1] + rm[2] + rm[3];
        out_graph[k] = st / mt;
    }
}

extern "C" void kernel_launch(void* const* d_in, const int* in_sizes, int n_in,
                              void* d_out, int out_size, void* d_ws, size_t ws_size,
                              hipStream_t stream) {
    const float* node = (const float*)d_in[0];   // [N, D]
    const float* mask = (const float*)d_in[1];   // [N, 1]
    const float* w    = (const float*)d_in[2];   // [K, D]
    float* out = (float*)d_out;

    int N = in_sizes[0] / D;                     // 200000

    // ws layout: crb bf16[K*D] | c2[K] | partial[NBLK*K] | maskpart[NBLK]
    __bf16* crb     = (__bf16*)d_ws;
    float* c2       = (float*)(crb + K * D);
    float* partial  = c2 + K;
    float* maskpart = partial + (size_t)NBLK * K;

    float* out_graph = out;        // [K]
    float* out_node  = out + K;    // [N, K]

    prep_kernel<<<K, 64, 0, stream>>>(w, crb, c2);
    main_kernel<<<NBLK, 256, 0, stream>>>(node, mask, crb, c2, out_node,
                                          partial, maskpart, N);
    reduce_kernel<<<K, 256, 0, stream>>>(partial, maskpart, out_graph, NBLK);
}